// Round 11
// baseline (88.961 us; speedup 1.0000x reference)
//
#include <hip/hip_runtime.h>
#include <math.h>

#define A_TOT 8400
#define NB 16
#define NG 32
#define NCH 144
#define NDFL 16
#define EPSF 1e-9f
#define CEPS 1e-7f
#define INV_PI2_4 0.40528473456935109f  /* 4/pi^2 */
#define NBLK2 2100
#define LSEG 512
#define KB_BLOCKS 64

// workspace layout (float32 indices)
#define OFF_GTBOX   0            /* NB*NG*4 = 2048 */
#define OFF_GTLAB   2048         /* 512 */
#define OFF_MASKGT  2560         /* 512 */
#define OFF_ATANGT  3072         /* 512 */
#define OFF_ACC     3584         /* 8: [0]=softplus total (atomicExch) */
#define OFF_CTRL    3592         /* 8 u32: [1]=barrier1 [2]=barrier2 [3]=ticket */
#define OFF_BCNT    3600         /* 16 counters, stride 16 u32 = 256 */
#define OFF_PART2   3856         /* 2112 per-block softplus partials */
#define OFF_PART6   5968         /* 256 kbig per-block partials */
#define OFF_POSM    6224         /* 512 gts x 8 floats: [0]=posAl [1]=posOv */
#define OFF_PBOX    10320        /* NB*A*4 grid units */
#define OFF_MPOS    547920       /* NB*A u32 */
#define OFF_LIST    682320       /* NB*LSEG u32 anchor ids */

__device__ __forceinline__ void locate(int a, int& loc, int& W, float& s, int& lvl, int& hw){
  if (a < 6400)      { lvl = 0; loc = a;        W = 80; s = 8.f;  hw = 6400; }
  else if (a < 8000) { lvl = 1; loc = a - 6400; W = 40; s = 16.f; hw = 1600; }
  else               { lvl = 2; loc = a - 8000; W = 20; s = 32.f; hw = 400;  }
}

__device__ __forceinline__ const float* level_ptr(const float* p3, const float* p4, const float* p5, int lvl){
  return lvl == 0 ? p3 : (lvl == 1 ? p4 : p5);
}

__device__ __forceinline__ float ciou_gp(float gx1,float gy1,float gx2,float gy2,float atg,
                                         float px1,float py1,float px2,float py2,float atp){
  float w1 = gx2-gx1, h1 = gy2-gy1+CEPS;
  float w2 = px2-px1, h2 = py2-py1+CEPS;
  float iw = fmaxf(fminf(gx2,px2)-fmaxf(gx1,px1), 0.f);
  float ih = fmaxf(fminf(gy2,py2)-fmaxf(gy1,py1), 0.f);
  float inter = iw*ih;
  float uni = w1*h1 + w2*h2 - inter + CEPS;
  float iou = inter/uni;
  float cw = fmaxf(gx2,px2)-fminf(gx1,px1);
  float ch = fmaxf(gy2,py2)-fminf(gy1,py1);
  float c2 = cw*cw + ch*ch + CEPS;
  float dx = px1+px2-gx1-gx2, dy = py1+py2-gy1-gy2;
  float rho2 = (dx*dx + dy*dy)*0.25f;
  float dv = atp - atg;
  float v = INV_PI2_4*dv*dv;
  float al = v/(v - iou + (1.f + CEPS));
  return iou - (rho2/c2 + v*al);
}

// ============ kernel A: barrier-light full-input pass + (last block) prep =======
__global__ __launch_bounds__(256) void k2x(const float* __restrict__ p3, const float* __restrict__ p4,
                          const float* __restrict__ p5, const float* __restrict__ tgt, int nt,
                          float* __restrict__ ws){
  int tid = threadIdx.x;
  int bx = blockIdx.x;
  if (bx == NBLK2){
    __shared__ int simg[256];
    float* gtbox  = ws + OFF_GTBOX;
    int*   gtlab  = (int*)(ws + OFF_GTLAB);
    float* maskgt = ws + OFF_MASKGT;
    float* atangt = ws + OFF_ATANGT;
    for (int i = tid; i < NB*NG*4; i += 256) gtbox[i] = 0.f;
    for (int i = tid; i < NB*NG; i += 256) gtlab[i] = 0;
    if (tid < 8){ (ws + OFF_ACC)[tid] = 0.f; ((unsigned*)(ws + OFF_CTRL))[tid] = 0u; }
    for (int i = tid; i < 256;  i += 256) ((unsigned*)(ws + OFF_BCNT))[i] = 0u;
    for (int i = tid; i < NB*NG*8; i += 256) (ws + OFF_POSM)[i] = 0.f;
    for (int i = tid; i < nt && i < 256; i += 256) simg[i] = (int)tgt[i*6];
    __syncthreads();
    for (int i = tid; i < nt && i < 256; i += 256){
      int b = simg[i];
      int r = 0;
      for (int j = 0; j < i; j++) r += (simg[j] == b);
      if (b >= 0 && b < NB && r < NG){
        float cls = tgt[i*6+1];
        float cx = tgt[i*6+2]*640.f, cy = tgt[i*6+3]*640.f;
        float w  = tgt[i*6+4]*640.f, h  = tgt[i*6+5]*640.f;
        int o = (b*NG + r)*4;
        gtbox[o+0] = cx - 0.5f*w; gtbox[o+1] = cy - 0.5f*h;
        gtbox[o+2] = cx + 0.5f*w; gtbox[o+3] = cy + 0.5f*h;
        gtlab[b*NG + r] = (int)cls;
      }
    }
    __syncthreads();
    for (int i = tid; i < NB*NG; i += 256){
      float x1 = gtbox[i*4], y1 = gtbox[i*4+1], x2 = gtbox[i*4+2], y2 = gtbox[i*4+3];
      maskgt[i] = ((x1+y1+x2+y2) > 0.f) ? 1.f : 0.f;
      atangt[i] = atanf((x2-x1)/(y2-y1+CEPS));
    }
    return;
  }
  __shared__ float redw[4];
  {
    int mp = bx*256 + tid;
    if (mp < NB*A_TOT) ((unsigned*)(ws + OFF_MPOS))[mp] = 0u;
  }
  const float* base; int grow0, hw, W, lvloff;
  if (bx < 1600)      { base = p3; grow0 = bx*64;        hw = 6400; W = 80; lvloff = 0; }
  else if (bx < 2000) { base = p4; grow0 = (bx-1600)*64; hw = 1600; W = 40; lvloff = 6400; }
  else                { base = p5; grow0 = (bx-2000)*64; hw = 400;  W = 20; lvloff = 8000; }

  const float4* src = (const float4*)base + (size_t)grow0*36;
  // DFL decode: thread t -> row r = t>>2, side f = t&3; 64B/lane contiguous
  {
    int r = tid >> 2, f = tid & 3;
    const float4* rp = src + r*36 + f*4;
    float4 v0 = rp[0], v1 = rp[1], v2 = rp[2], v3 = rp[3];
    float m = v0.x;
    m = fmaxf(m, v0.y); m = fmaxf(m, v0.z); m = fmaxf(m, v0.w);
    m = fmaxf(m, v1.x); m = fmaxf(m, v1.y); m = fmaxf(m, v1.z); m = fmaxf(m, v1.w);
    m = fmaxf(m, v2.x); m = fmaxf(m, v2.y); m = fmaxf(m, v2.z); m = fmaxf(m, v2.w);
    m = fmaxf(m, v3.x); m = fmaxf(m, v3.y); m = fmaxf(m, v3.z); m = fmaxf(m, v3.w);
    float e, se, swe;
    e = __expf(v0.x - m); se = e;            swe = 0.f;
    e = __expf(v0.y - m); se += e;           swe += e;
    e = __expf(v0.z - m); se += e;           swe = fmaf(2.f,  e, swe);
    e = __expf(v0.w - m); se += e;           swe = fmaf(3.f,  e, swe);
    e = __expf(v1.x - m); se += e;           swe = fmaf(4.f,  e, swe);
    e = __expf(v1.y - m); se += e;           swe = fmaf(5.f,  e, swe);
    e = __expf(v1.z - m); se += e;           swe = fmaf(6.f,  e, swe);
    e = __expf(v1.w - m); se += e;           swe = fmaf(7.f,  e, swe);
    e = __expf(v2.x - m); se += e;           swe = fmaf(8.f,  e, swe);
    e = __expf(v2.y - m); se += e;           swe = fmaf(9.f,  e, swe);
    e = __expf(v2.z - m); se += e;           swe = fmaf(10.f, e, swe);
    e = __expf(v2.w - m); se += e;           swe = fmaf(11.f, e, swe);
    e = __expf(v3.x - m); se += e;           swe = fmaf(12.f, e, swe);
    e = __expf(v3.y - m); se += e;           swe = fmaf(13.f, e, swe);
    e = __expf(v3.z - m); se += e;           swe = fmaf(14.f, e, swe);
    e = __expf(v3.w - m); se += e;           swe = fmaf(15.f, e, swe);
    float pdf = __fdividef(swe, se);
    float s1 = __shfl_xor(pdf, 1);
    float s2 = __shfl_xor(pdf, 2);
    float s3 = __shfl_xor(pdf, 3);
    if (f == 0){
      int grow = grow0 + r;
      int b = grow / hw, loc = grow - b*hw;
      float ax = (loc % W) + 0.5f, ay = (loc / W) + 0.5f;
      float4 pb;
      pb.x = ax - pdf; pb.y = ay - s1; pb.z = ax + s2; pb.w = ay + s3;
      ((float4*)(ws + OFF_PBOX))[(size_t)b*A_TOT + lvloff + loc] = pb;
    }
  }
  // softplus over score channels
  float sp = 0.f;
  #pragma unroll
  for (int i = 0; i < 5; i++){
    int id = i*256 + tid;
    int r = id/20, q = id - r*20;
    float4 v = src[r*36 + 16 + q];
    #pragma unroll
    for (int e2 = 0; e2 < 4; e2++){
      float x = (&v.x)[e2];
      float ex = __expf(-fabsf(x));
      sp += fmaxf(x, 0.f) + __logf(1.f + ex);
    }
  }
  #pragma unroll
  for (int st = 1; st < 64; st <<= 1) sp += __shfl_xor(sp, st);
  int wid = tid >> 6, lane = tid & 63;
  if (lane == 0) redw[wid] = sp;
  __syncthreads();
  if (tid == 0) (ws + OFF_PART2)[bx] = redw[0]+redw[1]+redw[2]+redw[3];
}

// ============ kernel B: topk + barrier + resolve + barrier + losses =============
#define REG_K 15
__global__ __launch_bounds__(512) void kbig(const float* __restrict__ p3, const float* __restrict__ p4,
                        const float* __restrict__ p5, float* __restrict__ ws, float* __restrict__ out){
  __shared__ float redw[32];
  __shared__ float fin[4];
  __shared__ int lastf;
  int tid = threadIdx.x;
  int lane = tid & 63, wid = tid >> 6;
  int bx = blockIdx.x;

  // ---- phase 1: wave-per-(b,n) top-10 ----
  {
    int g = bx*8 + wid;
    int b = g >> 5, n = g & 31;
    float mk = ws[OFF_MASKGT + b*NG + n];
    if (mk > 0.f){
      int lab = ((const int*)(ws + OFF_GTLAB))[b*NG + n];
      int ch = 64 + lab;
      float atg = ws[OFF_ATANGT + b*NG + n];
      const float* gt = ws + OFF_GTBOX + (b*NG + n)*4;
      float gx1 = gt[0], gy1 = gt[1], gx2 = gt[2], gy2 = gt[3];
      int clo0 = max(0, (int)floorf(gx1*0.125f   - 0.5f));
      int chi0 = min(79,(int)ceilf (gx2*0.125f   - 0.5f));
      int rlo0 = max(0, (int)floorf(gy1*0.125f   - 0.5f));
      int rhi0 = min(79,(int)ceilf (gy2*0.125f   - 0.5f));
      int clo1 = max(0, (int)floorf(gx1*0.0625f  - 0.5f));
      int chi1 = min(39,(int)ceilf (gx2*0.0625f  - 0.5f));
      int rlo1 = max(0, (int)floorf(gy1*0.0625f  - 0.5f));
      int rhi1 = min(39,(int)ceilf (gy2*0.0625f  - 0.5f));
      int clo2 = max(0, (int)floorf(gx1*0.03125f - 0.5f));
      int chi2 = min(19,(int)ceilf (gx2*0.03125f - 0.5f));
      int rlo2 = max(0, (int)floorf(gy1*0.03125f - 0.5f));
      int rhi2 = min(19,(int)ceilf (gy2*0.03125f - 0.5f));
      int nc0 = chi0-clo0+1, nr0 = rhi0-rlo0+1;
      int nc1 = chi1-clo1+1, nr1 = rhi1-rlo1+1;
      int nc2 = chi2-clo2+1, nr2 = rhi2-rlo2+1;
      int cnt0 = (nc0>0 && nr0>0) ? nc0*nr0 : 0;
      int cnt1 = (nc1>0 && nr1>0) ? nc1*nr1 : 0;
      int cnt2 = (nc2>0 && nr2>0) ? nc2*nr2 : 0;
      const int CAP = 64*REG_K;
      if (16+cnt0 > CAP)           cnt0 = CAP-16;
      if (16+cnt0+cnt1 > CAP)      cnt1 = CAP-16-cnt0;
      if (16+cnt0+cnt1+cnt2 > CAP) cnt2 = CAP-16-cnt0-cnt1;
      int b1 = 16 + cnt0, b2 = b1 + cnt1;
      int tot = b2 + cnt2;
      float mv[REG_K]; int mi[REG_K];
      #pragma unroll
      for (int cc = 0; cc < REG_K; cc++){
        mv[cc] = -1e30f; mi[cc] = 0x7fffffff;
        int c = cc*64 + lane;
        if (c < tot){
          int aidx, loc, W, hw; float s; const float* bp; bool dup = false;
          if (c < 16)     { aidx = c; loc = c; W = 80; s = 8.f;  hw = 6400; bp = p3; }
          else if (c < b1){ int j = c-16; int rr = j/nc0; loc = (rlo0+rr)*80 + clo0 + (j - rr*nc0);
                            aidx = loc;        W = 80; s = 8.f;  hw = 6400; bp = p3; dup = (aidx < 16); }
          else if (c < b2){ int j = c-b1; int rr = j/nc1; loc = (rlo1+rr)*40 + clo1 + (j - rr*nc1);
                            aidx = 6400 + loc; W = 40; s = 16.f; hw = 1600; bp = p4; }
          else            { int j = c-b2; int rr = j/nc2; loc = (rlo2+rr)*20 + clo2 + (j - rr*nc2);
                            aidx = 8000 + loc; W = 20; s = 32.f; hw = 400;  bp = p5; }
          if (dup){ mv[cc] = -1.f; mi[cc] = 0x3fffffff; }
          else {
            float m = 0.f;
            float axi = ((loc % W) + 0.5f)*s, ayi = ((loc / W) + 0.5f)*s;
            float dmin = fminf(fminf(axi-gx1, ayi-gy1), fminf(gx2-axi, gy2-ayi));
            if (dmin > EPSF){
              float4 pg = ((const float4*)(ws + OFF_PBOX))[(size_t)b*A_TOT + aidx];
              float px1 = pg.x*s, py1 = pg.y*s, px2 = pg.z*s, py2 = pg.w*s;
              float atp = atanf((px2-px1)/(py2-py1+CEPS));
              float o = fmaxf(ciou_gp(gx1,gy1,gx2,gy2,atg, px1,py1,px2,py2,atp), 0.f);
              float l = bp[((size_t)b*hw + loc)*NCH + ch];
              float sc = __frcp_rn(1.f + __expf(-l));
              float o2 = o*o;
              m = sqrtf(sc)*o2*o2*o2;
            }
            mv[cc] = m; mi[cc] = aidx;
          }
        }
      }
      float top0 = 0.f;
      int mytop = -1;
      #pragma unroll
      for (int k = 0; k < 10; k++){
        float bv = -1e30f; int bai = 0x7fffffff;
        #pragma unroll
        for (int cc = 0; cc < REG_K; cc++){
          if (mv[cc] > bv || (mv[cc] == bv && mi[cc] < bai)){ bv = mv[cc]; bai = mi[cc]; }
        }
        #pragma unroll
        for (int st = 1; st < 64; st <<= 1){
          float ov = __shfl_xor(bv, st);
          int  oai = __shfl_xor(bai, st);
          if (ov > bv || (ov == bv && oai < bai)){ bv = ov; bai = oai; }
        }
        if (k == 0) top0 = bv;
        if (lane == k) mytop = bai;
        #pragma unroll
        for (int cc = 0; cc < REG_K; cc++){
          if (mi[cc] == bai) mv[cc] = -2.f;
        }
      }
      bool want = (lane < 10) && (top0 > EPSF) && (mytop >= 0) && (mytop < A_TOT);
      if (want){
        int loc, W, lvl, hw; float s;
        locate(mytop, loc, W, s, lvl, hw);
        float axi = ((loc % W) + 0.5f)*s, ayi = ((loc / W) + 0.5f)*s;
        float dmin = fminf(fminf(axi-gx1, ayi-gy1), fminf(gx2-axi, gy2-ayi));
        want = (dmin > EPSF);
      }
      unsigned old = 0u;
      if (want) old = atomicOr((unsigned*)(ws + OFF_MPOS) + (size_t)b*A_TOT + mytop, 1u << n);
      want = want && (old == 0u);
      unsigned long long m64 = __ballot(want);
      if (want){
        int lead = __ffsll((long long)m64) - 1;
        unsigned base = 0;
        if (lane == lead) base = atomicAdd((unsigned*)(ws + OFF_BCNT) + b*16, (unsigned)__popcll(m64));
        base = __shfl(base, lead);
        unsigned slot = base + (unsigned)__popcll(m64 & ((1ull << lane) - 1ull));
        if (slot < LSEG) ((unsigned*)(ws + OFF_LIST))[b*LSEG + slot] = (unsigned)mytop;
      }
    }
  }
  // block 0: fold softplus partials (overlaps other blocks' topk)
  if (bx == 0){
    float v = 0.f;
    for (int j = tid; j < NBLK2; j += 512) v += (ws + OFF_PART2)[j];
    #pragma unroll
    for (int st = 1; st < 64; st <<= 1) v += __shfl_xor(v, st);
    if (lane == 0) redw[wid] = v;
    __syncthreads();
    if (tid == 0){
      float t = 0.f;
      #pragma unroll
      for (int w = 0; w < 8; w++) t += redw[w];
      atomicExch(ws + OFF_ACC + 0, t);
    }
  }
  // ---- grid barrier 1 (64 co-resident blocks) ----
  __syncthreads();
  if (tid == 0){
    __threadfence();
    atomicAdd((unsigned*)(ws + OFF_CTRL) + 1, 1u);
    while (atomicAdd((unsigned*)(ws + OFF_CTRL) + 1, 0u) < KB_BLOCKS){ __builtin_amdgcn_s_sleep(1); }
  }
  __syncthreads();
  __threadfence();
  // ---- phase 2: resolve (block bx handles image bx; only bx<NB active) ----
  bool valid = false; int a = 0;
  int ns = 0; float av = 0.f;
  int loc=0, W=80, lvl=0, hw=6400; float sfac=8.f;
  if (bx < NB){
    unsigned cntb = atomicAdd((unsigned*)(ws + OFF_BCNT) + bx*16, 0u);
    if ((unsigned)tid < cntb && cntb <= LSEG){
      valid = true;
      a = (int)((unsigned*)(ws + OFF_LIST))[bx*LSEG + tid];
    }
  }
  if (valid){
    unsigned bits = ((const unsigned*)(ws + OFF_MPOS))[(size_t)bx*A_TOT + a];
    locate(a, loc, W, sfac, lvl, hw);
    float4 pg = ((const float4*)(ws + OFF_PBOX))[(size_t)bx*A_TOT + a];
    float px1 = pg.x*sfac, py1 = pg.y*sfac, px2 = pg.z*sfac, py2 = pg.w*sfac;
    float atp = atanf((px2-px1)/(py2-py1+CEPS));
    if (__popc(bits) == 1){ ns = __ffs(bits) - 1; }
    else {
      float bv = -1.f; ns = 0;
      for (int nn = 0; nn < NG; nn++){
        const float* g = ws + OFF_GTBOX + (bx*NG + nn)*4;
        float atg = ws[OFF_ATANGT + bx*NG + nn];
        float o = fmaxf(ciou_gp(g[0],g[1],g[2],g[3],atg, px1,py1,px2,py2,atp), 0.f);
        if (o > bv){ bv = o; ns = nn; }
      }
    }
    const float* g = ws + OFF_GTBOX + (bx*NG + ns)*4;
    float atg = ws[OFF_ATANGT + bx*NG + ns];
    float o = fmaxf(ciou_gp(g[0],g[1],g[2],g[3],atg, px1,py1,px2,py2,atp), 0.f);
    int lab = ((const int*)(ws + OFF_GTLAB))[bx*NG + ns];
    float l = level_ptr(p3,p4,p5,lvl)[((size_t)bx*hw + loc)*NCH + 64 + lab];
    float sc = __frcp_rn(1.f + __expf(-l));
    float o2 = o*o;
    av = sqrtf(sc)*o2*o2*o2;
    unsigned* pm = (unsigned*)(ws + OFF_POSM) + (bx*NG + ns)*8;
    atomicMax(pm + 0, __float_as_uint(av));
    atomicMax(pm + 1, __float_as_uint(o));
  }
  // ---- grid barrier 2 ----
  __syncthreads();
  if (tid == 0){
    __threadfence();
    atomicAdd((unsigned*)(ws + OFF_CTRL) + 2, 1u);
    while (atomicAdd((unsigned*)(ws + OFF_CTRL) + 2, 0u) < KB_BLOCKS){ __builtin_amdgcn_s_sleep(1); }
  }
  __syncthreads();
  __threadfence();
  // ---- phase 3: losses ----
  float bcec = 0.f, boxl = 0.f, dfll = 0.f, tsc = 0.f;
  if (valid){
    unsigned* pm = (unsigned*)(ws + OFF_POSM) + (bx*NG + ns)*8;
    float pa = __uint_as_float(atomicOr(pm + 0, 0u));
    float po = __uint_as_float(atomicOr(pm + 1, 0u));
    float norm = av * po / (pa + EPSF);
    const float* row = level_ptr(p3,p4,p5,lvl) + ((size_t)bx*hw + loc)*NCH;
    int lab = ((const int*)(ws + OFF_GTLAB))[bx*NG + ns];
    if (lab < 0) lab = 0;
    tsc = norm;
    bcec = -row[64 + lab]*norm;
    float4 pb = ((const float4*)(ws + OFF_PBOX))[(size_t)bx*A_TOT + a];
    const float* g = ws + OFF_GTBOX + (bx*NG + ns)*4;
    float inv_s = 1.f/sfac;
    float tx1 = g[0]*inv_s, ty1 = g[1]*inv_s, tx2 = g[2]*inv_s, ty2 = g[3]*inv_s;
    float w1 = pb.z-pb.x, h1 = pb.w-pb.y+CEPS;
    float w2 = tx2-tx1,   h2 = ty2-ty1+CEPS;
    float iw = fmaxf(fminf(pb.z,tx2)-fmaxf(pb.x,tx1), 0.f);
    float ih = fmaxf(fminf(pb.w,ty2)-fmaxf(pb.y,ty1), 0.f);
    float inter = iw*ih;
    float uni = w1*h1 + w2*h2 - inter + CEPS;
    float iou = inter/uni;
    float cw = fmaxf(pb.z,tx2)-fminf(pb.x,tx1);
    float ch = fmaxf(pb.w,ty2)-fminf(pb.y,ty1);
    float c2 = cw*cw + ch*ch + CEPS;
    float dx = tx1+tx2-pb.x-pb.z, dy = ty1+ty2-pb.y-pb.w;
    float rho2 = (dx*dx + dy*dy)*0.25f;
    float dv = atanf(w2/h2) - atanf(w1/h1);
    float v = INV_PI2_4*dv*dv;
    float al = v/(v - iou + (1.f + CEPS));
    float ci = iou - (rho2/c2 + v*al);
    boxl = (1.f - ci)*norm;
    float ax = (loc % W) + 0.5f, ay = (loc / W) + 0.5f;
    float ltrb[4] = {ax - tx1, ay - ty1, tx2 - ax, ty2 - ay};
    float ds = 0.f;
    #pragma unroll
    for (int f = 0; f < 4; f++){
      float val = fminf(fmaxf(ltrb[f], 0.f), (float)NDFL - 1.01f);
      int tl = (int)val;
      float wl = (float)(tl + 1) - val;
      float x[16];
      const float4* r4 = (const float4*)(row + f*16);
      #pragma unroll
      for (int q = 0; q < 4; q++){ float4 vv = r4[q]; x[q*4]=vv.x; x[q*4+1]=vv.y; x[q*4+2]=vv.z; x[q*4+3]=vv.w; }
      float m = x[0];
      #pragma unroll
      for (int j = 1; j < 16; j++) m = fmaxf(m, x[j]);
      float se = 0.f;
      #pragma unroll
      for (int j = 0; j < 16; j++) se += __expf(x[j]-m);
      float lse = m + __logf(se);
      float xl = 0.f, xr = 0.f;
      #pragma unroll
      for (int j = 0; j < 16; j++){
        xl = (j == tl)   ? x[j] : xl;
        xr = (j == tl+1) ? x[j] : xr;
      }
      ds += (lse - xl)*wl + (lse - xr)*(1.f - wl);
    }
    dfll = ds*0.25f*norm;
  }
  float vals[4] = {bcec, boxl, dfll, tsc};
  #pragma unroll
  for (int q = 0; q < 4; q++){
    float v = vals[q];
    #pragma unroll
    for (int st = 1; st < 64; st <<= 1) v += __shfl_xor(v, st);
    if (lane == 0) redw[wid*4 + q] = v;
  }
  if (tid == 0) lastf = 0;
  __syncthreads();
  if (tid < 4){
    float v = 0.f;
    #pragma unroll
    for (int w = 0; w < 8; w++) v += redw[w*4 + tid];
    atomicExch(ws + OFF_PART6 + bx*4 + tid, v);
  }
  __syncthreads();
  if (tid == 0){
    __threadfence();
    unsigned tkt = atomicAdd((unsigned*)(ws + OFF_CTRL) + 3, 1u);
    if (tkt == KB_BLOCKS - 1) lastf = 1;
  }
  __syncthreads();
  if (lastf){
    if (tid < 4) fin[tid] = 0.f;
    __syncthreads();
    if (tid < 4*KB_BLOCKS){
      float v = atomicAdd(ws + OFF_PART6 + tid, 0.f);
      atomicAdd(&fin[tid & 3], v);
    }
    __syncthreads();
    if (tid == 0){
      float sp = atomicAdd(ws + OFF_ACC + 0, 0.f);
      float tss = fmaxf(fin[3], 1.f);
      out[0] = (0.5f*(sp + fin[0]) + 7.5f*fin[1] + 1.5f*fin[2]) / tss;
    }
  }
}

extern "C" void kernel_launch(void* const* d_in, const int* in_sizes, int n_in,
                              void* d_out, int out_size, void* d_ws, size_t ws_size,
                              hipStream_t stream) {
  const float* p3 = (const float*)d_in[0];
  const float* p4 = (const float*)d_in[1];
  const float* p5 = (const float*)d_in[2];
  const float* tg = (const float*)d_in[3];
  int nt = in_sizes[3] / 6;
  float* ws = (float*)d_ws;
  float* out = (float*)d_out;

  k2x<<<NBLK2 + 1, 256, 0, stream>>>(p3, p4, p5, tg, nt, ws);
  kbig<<<KB_BLOCKS, 512, 0, stream>>>(p3, p4, p5, ws, out);
}

// Round 12
// 76.721 us; speedup vs baseline: 1.1595x; 1.1595x over previous
//
#include <hip/hip_runtime.h>
#include <math.h>

#define A_TOT 8400
#define NB 16
#define NG 32
#define NCH 144
#define NDFL 16
#define EPSF 1e-9f
#define CEPS 1e-7f
#define INV_PI2_4 0.40528473456935109f  /* 4/pi^2 */
#define NBLK2 2100
#define LSEG 512
#define K56_BLOCKS 32

#define LOADU(p)  __hip_atomic_load((p), __ATOMIC_ACQUIRE, __HIP_MEMORY_SCOPE_AGENT)
#define LOADF(p)  __hip_atomic_load((p), __ATOMIC_ACQUIRE, __HIP_MEMORY_SCOPE_AGENT)

// workspace layout (float32 indices)
#define OFF_GTBOX   0            /* NB*NG*4 = 2048 */
#define OFF_GTLAB   2048         /* 512 */
#define OFF_MASKGT  2560         /* 512 */
#define OFF_ATANGT  3072         /* 512 */
#define OFF_ACC     3584         /* 8: [0]=softplus total */
#define OFF_CTRL    3592         /* 8 u32: [1]=barrierA [2]=ticketB */
#define OFF_BCNT    3600         /* 16 counters, stride 16 u32 = 256 */
#define OFF_PART2   3856         /* 2112 per-block softplus partials */
#define OFF_PART6   5968         /* 128 k56 per-block partials */
#define OFF_POSM    6224         /* 512 gts x 8 floats: [0]=posAl [1]=posOv */
#define OFF_PBOX    10320        /* NB*A*4 grid units */
#define OFF_MPOS    547920       /* NB*A u32 */
#define OFF_LIST    682320       /* NB*LSEG u32 anchor ids */

__device__ __forceinline__ void locate(int a, int& loc, int& W, float& s, int& lvl, int& hw){
  if (a < 6400)      { lvl = 0; loc = a;        W = 80; s = 8.f;  hw = 6400; }
  else if (a < 8000) { lvl = 1; loc = a - 6400; W = 40; s = 16.f; hw = 1600; }
  else               { lvl = 2; loc = a - 8000; W = 20; s = 32.f; hw = 400;  }
}

__device__ __forceinline__ const float* level_ptr(const float* p3, const float* p4, const float* p5, int lvl){
  return lvl == 0 ? p3 : (lvl == 1 ? p4 : p5);
}

__device__ __forceinline__ float ciou_gp(float gx1,float gy1,float gx2,float gy2,float atg,
                                         float px1,float py1,float px2,float py2,float atp){
  float w1 = gx2-gx1, h1 = gy2-gy1+CEPS;
  float w2 = px2-px1, h2 = py2-py1+CEPS;
  float iw = fmaxf(fminf(gx2,px2)-fmaxf(gx1,px1), 0.f);
  float ih = fmaxf(fminf(gy2,py2)-fmaxf(gy1,py1), 0.f);
  float inter = iw*ih;
  float uni = w1*h1 + w2*h2 - inter + CEPS;
  float iou = inter/uni;
  float cw = fmaxf(gx2,px2)-fminf(gx1,px1);
  float ch = fmaxf(gy2,py2)-fminf(gy1,py1);
  float c2 = cw*cw + ch*ch + CEPS;
  float dx = px1+px2-gx1-gx2, dy = py1+py2-gy1-gy2;
  float rho2 = (dx*dx + dy*dy)*0.25f;
  float dv = atp - atg;
  float v = INV_PI2_4*dv*dv;
  float al = v/(v - iou + (1.f + CEPS));
  return iou - (rho2/c2 + v*al);
}

// ============ kernel A: barrier-light full-input pass + (last block) prep =======
__global__ __launch_bounds__(256) void k2x(const float* __restrict__ p3, const float* __restrict__ p4,
                          const float* __restrict__ p5, const float* __restrict__ tgt, int nt,
                          float* __restrict__ ws){
  int tid = threadIdx.x;
  int bx = blockIdx.x;
  if (bx == NBLK2){
    __shared__ int simg[256];
    float* gtbox  = ws + OFF_GTBOX;
    int*   gtlab  = (int*)(ws + OFF_GTLAB);
    float* maskgt = ws + OFF_MASKGT;
    float* atangt = ws + OFF_ATANGT;
    for (int i = tid; i < NB*NG*4; i += 256) gtbox[i] = 0.f;
    for (int i = tid; i < NB*NG; i += 256) gtlab[i] = 0;
    if (tid < 8){ (ws + OFF_ACC)[tid] = 0.f; ((unsigned*)(ws + OFF_CTRL))[tid] = 0u; }
    for (int i = tid; i < 256;  i += 256) ((unsigned*)(ws + OFF_BCNT))[i] = 0u;
    for (int i = tid; i < NB*NG*8; i += 256) (ws + OFF_POSM)[i] = 0.f;
    for (int i = tid; i < nt && i < 256; i += 256) simg[i] = (int)tgt[i*6];
    __syncthreads();
    for (int i = tid; i < nt && i < 256; i += 256){
      int b = simg[i];
      int r = 0;
      for (int j = 0; j < i; j++) r += (simg[j] == b);
      if (b >= 0 && b < NB && r < NG){
        float cls = tgt[i*6+1];
        float cx = tgt[i*6+2]*640.f, cy = tgt[i*6+3]*640.f;
        float w  = tgt[i*6+4]*640.f, h  = tgt[i*6+5]*640.f;
        int o = (b*NG + r)*4;
        gtbox[o+0] = cx - 0.5f*w; gtbox[o+1] = cy - 0.5f*h;
        gtbox[o+2] = cx + 0.5f*w; gtbox[o+3] = cy + 0.5f*h;
        gtlab[b*NG + r] = (int)cls;
      }
    }
    __syncthreads();
    for (int i = tid; i < NB*NG; i += 256){
      float x1 = gtbox[i*4], y1 = gtbox[i*4+1], x2 = gtbox[i*4+2], y2 = gtbox[i*4+3];
      maskgt[i] = ((x1+y1+x2+y2) > 0.f) ? 1.f : 0.f;
      atangt[i] = atanf((x2-x1)/(y2-y1+CEPS));
    }
    return;
  }
  __shared__ float redw[4];
  {
    int mp = bx*256 + tid;
    if (mp < NB*A_TOT) ((unsigned*)(ws + OFF_MPOS))[mp] = 0u;
  }
  const float* base; int grow0, hw, W, lvloff;
  if (bx < 1600)      { base = p3; grow0 = bx*64;        hw = 6400; W = 80; lvloff = 0; }
  else if (bx < 2000) { base = p4; grow0 = (bx-1600)*64; hw = 1600; W = 40; lvloff = 6400; }
  else                { base = p5; grow0 = (bx-2000)*64; hw = 400;  W = 20; lvloff = 8000; }

  const float4* src = (const float4*)base + (size_t)grow0*36;
  // DFL decode: thread t -> row r = t>>2, side f = t&3; 64B/lane contiguous
  {
    int r = tid >> 2, f = tid & 3;
    const float4* rp = src + r*36 + f*4;
    float4 v0 = rp[0], v1 = rp[1], v2 = rp[2], v3 = rp[3];
    float m = v0.x;
    m = fmaxf(m, v0.y); m = fmaxf(m, v0.z); m = fmaxf(m, v0.w);
    m = fmaxf(m, v1.x); m = fmaxf(m, v1.y); m = fmaxf(m, v1.z); m = fmaxf(m, v1.w);
    m = fmaxf(m, v2.x); m = fmaxf(m, v2.y); m = fmaxf(m, v2.z); m = fmaxf(m, v2.w);
    m = fmaxf(m, v3.x); m = fmaxf(m, v3.y); m = fmaxf(m, v3.z); m = fmaxf(m, v3.w);
    float e, se, swe;
    e = __expf(v0.x - m); se = e;            swe = 0.f;
    e = __expf(v0.y - m); se += e;           swe += e;
    e = __expf(v0.z - m); se += e;           swe = fmaf(2.f,  e, swe);
    e = __expf(v0.w - m); se += e;           swe = fmaf(3.f,  e, swe);
    e = __expf(v1.x - m); se += e;           swe = fmaf(4.f,  e, swe);
    e = __expf(v1.y - m); se += e;           swe = fmaf(5.f,  e, swe);
    e = __expf(v1.z - m); se += e;           swe = fmaf(6.f,  e, swe);
    e = __expf(v1.w - m); se += e;           swe = fmaf(7.f,  e, swe);
    e = __expf(v2.x - m); se += e;           swe = fmaf(8.f,  e, swe);
    e = __expf(v2.y - m); se += e;           swe = fmaf(9.f,  e, swe);
    e = __expf(v2.z - m); se += e;           swe = fmaf(10.f, e, swe);
    e = __expf(v2.w - m); se += e;           swe = fmaf(11.f, e, swe);
    e = __expf(v3.x - m); se += e;           swe = fmaf(12.f, e, swe);
    e = __expf(v3.y - m); se += e;           swe = fmaf(13.f, e, swe);
    e = __expf(v3.z - m); se += e;           swe = fmaf(14.f, e, swe);
    e = __expf(v3.w - m); se += e;           swe = fmaf(15.f, e, swe);
    float pdf = __fdividef(swe, se);
    float s1 = __shfl_xor(pdf, 1);
    float s2 = __shfl_xor(pdf, 2);
    float s3 = __shfl_xor(pdf, 3);
    if (f == 0){
      int grow = grow0 + r;
      int b = grow / hw, loc = grow - b*hw;
      float ax = (loc % W) + 0.5f, ay = (loc / W) + 0.5f;
      float4 pb;
      pb.x = ax - pdf; pb.y = ay - s1; pb.z = ax + s2; pb.w = ay + s3;
      ((float4*)(ws + OFF_PBOX))[(size_t)b*A_TOT + lvloff + loc] = pb;
    }
  }
  // softplus over score channels
  float sp = 0.f;
  #pragma unroll
  for (int i = 0; i < 5; i++){
    int id = i*256 + tid;
    int r = id/20, q = id - r*20;
    float4 v = src[r*36 + 16 + q];
    #pragma unroll
    for (int e2 = 0; e2 < 4; e2++){
      float x = (&v.x)[e2];
      float ex = __expf(-fabsf(x));
      sp += fmaxf(x, 0.f) + __logf(1.f + ex);
    }
  }
  #pragma unroll
  for (int st = 1; st < 64; st <<= 1) sp += __shfl_xor(sp, st);
  int wid = tid >> 6, lane = tid & 63;
  if (lane == 0) redw[wid] = sp;
  __syncthreads();
  if (tid == 0) (ws + OFF_PART2)[bx] = redw[0]+redw[1]+redw[2]+redw[3];
}

// ============ kernel B: wave-per-(b,n) top-10, per-image list append ============
#define REG_K 15
__global__ __launch_bounds__(512) void k4x(const float* __restrict__ p3, const float* __restrict__ p4,
                        const float* __restrict__ p5, float* __restrict__ ws){
  int tid = threadIdx.x;
  int lane = tid & 63;
  int g = blockIdx.x*8 + (tid >> 6);
  int b = g >> 5, n = g & 31;
  float mk = ws[OFF_MASKGT + b*NG + n];
  if (mk <= 0.f) return;
  int lab = ((const int*)(ws + OFF_GTLAB))[b*NG + n];
  int ch = 64 + lab;
  float atg = ws[OFF_ATANGT + b*NG + n];
  const float* gt = ws + OFF_GTBOX + (b*NG + n)*4;
  float gx1 = gt[0], gy1 = gt[1], gx2 = gt[2], gy2 = gt[3];

  int clo0 = max(0, (int)floorf(gx1*0.125f   - 0.5f));
  int chi0 = min(79,(int)ceilf (gx2*0.125f   - 0.5f));
  int rlo0 = max(0, (int)floorf(gy1*0.125f   - 0.5f));
  int rhi0 = min(79,(int)ceilf (gy2*0.125f   - 0.5f));
  int clo1 = max(0, (int)floorf(gx1*0.0625f  - 0.5f));
  int chi1 = min(39,(int)ceilf (gx2*0.0625f  - 0.5f));
  int rlo1 = max(0, (int)floorf(gy1*0.0625f  - 0.5f));
  int rhi1 = min(39,(int)ceilf (gy2*0.0625f  - 0.5f));
  int clo2 = max(0, (int)floorf(gx1*0.03125f - 0.5f));
  int chi2 = min(19,(int)ceilf (gx2*0.03125f - 0.5f));
  int rlo2 = max(0, (int)floorf(gy1*0.03125f - 0.5f));
  int rhi2 = min(19,(int)ceilf (gy2*0.03125f - 0.5f));
  int nc0 = chi0-clo0+1, nr0 = rhi0-rlo0+1;
  int nc1 = chi1-clo1+1, nr1 = rhi1-rlo1+1;
  int nc2 = chi2-clo2+1, nr2 = rhi2-rlo2+1;
  int cnt0 = (nc0>0 && nr0>0) ? nc0*nr0 : 0;
  int cnt1 = (nc1>0 && nr1>0) ? nc1*nr1 : 0;
  int cnt2 = (nc2>0 && nr2>0) ? nc2*nr2 : 0;
  const int CAP = 64*REG_K;
  if (16+cnt0 > CAP)           cnt0 = CAP-16;
  if (16+cnt0+cnt1 > CAP)      cnt1 = CAP-16-cnt0;
  if (16+cnt0+cnt1+cnt2 > CAP) cnt2 = CAP-16-cnt0-cnt1;
  int b1 = 16 + cnt0, b2 = b1 + cnt1;
  int tot = b2 + cnt2;

  float mv[REG_K]; int mi[REG_K];
  #pragma unroll
  for (int cc = 0; cc < REG_K; cc++){
    mv[cc] = -1e30f; mi[cc] = 0x7fffffff;
    int c = cc*64 + lane;
    if (c < tot){
      int aidx, loc, W, hw; float s; const float* bp; bool dup = false;
      if (c < 16)     { aidx = c; loc = c; W = 80; s = 8.f;  hw = 6400; bp = p3; }
      else if (c < b1){ int j = c-16; int rr = j/nc0; loc = (rlo0+rr)*80 + clo0 + (j - rr*nc0);
                        aidx = loc;        W = 80; s = 8.f;  hw = 6400; bp = p3; dup = (aidx < 16); }
      else if (c < b2){ int j = c-b1; int rr = j/nc1; loc = (rlo1+rr)*40 + clo1 + (j - rr*nc1);
                        aidx = 6400 + loc; W = 40; s = 16.f; hw = 1600; bp = p4; }
      else            { int j = c-b2; int rr = j/nc2; loc = (rlo2+rr)*20 + clo2 + (j - rr*nc2);
                        aidx = 8000 + loc; W = 20; s = 32.f; hw = 400;  bp = p5; }
      if (dup){ mv[cc] = -1.f; mi[cc] = 0x3fffffff; }
      else {
        float m = 0.f;
        float axi = ((loc % W) + 0.5f)*s, ayi = ((loc / W) + 0.5f)*s;
        float dmin = fminf(fminf(axi-gx1, ayi-gy1), fminf(gx2-axi, gy2-ayi));
        if (dmin > EPSF){
          float4 pg = ((const float4*)(ws + OFF_PBOX))[(size_t)b*A_TOT + aidx];
          float px1 = pg.x*s, py1 = pg.y*s, px2 = pg.z*s, py2 = pg.w*s;
          float atp = atanf((px2-px1)/(py2-py1+CEPS));
          float o = fmaxf(ciou_gp(gx1,gy1,gx2,gy2,atg, px1,py1,px2,py2,atp), 0.f);
          float l = bp[((size_t)b*hw + loc)*NCH + ch];
          float sc = __frcp_rn(1.f + __expf(-l));
          float o2 = o*o;
          m = sqrtf(sc)*o2*o2*o2;
        }
        mv[cc] = m; mi[cc] = aidx;
      }
    }
  }
  float top0 = 0.f;
  int mytop = -1;
  #pragma unroll
  for (int k = 0; k < 10; k++){
    float bv = -1e30f; int bai = 0x7fffffff;
    #pragma unroll
    for (int cc = 0; cc < REG_K; cc++){
      if (mv[cc] > bv || (mv[cc] == bv && mi[cc] < bai)){ bv = mv[cc]; bai = mi[cc]; }
    }
    #pragma unroll
    for (int st = 1; st < 64; st <<= 1){
      float ov = __shfl_xor(bv, st);
      int  oai = __shfl_xor(bai, st);
      if (ov > bv || (ov == bv && oai < bai)){ bv = ov; bai = oai; }
    }
    if (k == 0) top0 = bv;
    if (lane == k) mytop = bai;
    #pragma unroll
    for (int cc = 0; cc < REG_K; cc++){
      if (mi[cc] == bai) mv[cc] = -2.f;
    }
  }
  bool want = (lane < 10) && (top0 > EPSF) && (mytop >= 0) && (mytop < A_TOT);
  if (want){
    int loc, W, lvl, hw; float s;
    locate(mytop, loc, W, s, lvl, hw);
    float axi = ((loc % W) + 0.5f)*s, ayi = ((loc / W) + 0.5f)*s;
    float dmin = fminf(fminf(axi-gx1, ayi-gy1), fminf(gx2-axi, gy2-ayi));
    want = (dmin > EPSF);
  }
  unsigned old = 0u;
  if (want) old = atomicOr((unsigned*)(ws + OFF_MPOS) + (size_t)b*A_TOT + mytop, 1u << n);
  want = want && (old == 0u);
  unsigned long long m64 = __ballot(want);
  if (want){
    int lead = __ffsll((long long)m64) - 1;
    unsigned base = 0;
    if (lane == lead) base = atomicAdd((unsigned*)(ws + OFF_BCNT) + b*16, (unsigned)__popcll(m64));
    base = __shfl(base, lead);
    unsigned slot = base + (unsigned)__popcll(m64 & ((1ull << lane) - 1ull));
    if (slot < LSEG) ((unsigned*)(ws + OFF_LIST))[b*LSEG + slot] = (unsigned)mytop;
  }
}

// ============ kernel C: resolve + internal barrier + losses + combine ===========
__global__ __launch_bounds__(256) void k56x(const float* __restrict__ p3, const float* __restrict__ p4,
                        const float* __restrict__ p5, float* __restrict__ ws, float* __restrict__ out){
  __shared__ float redw[16];
  __shared__ float fin[4];
  __shared__ int lastf;
  __shared__ unsigned cnt_s;
  int tid = threadIdx.x;
  int lane = tid & 63, wid = tid >> 6;
  int s_id = blockIdx.x*256 + tid;
  int b = s_id >> 9, i = s_id & (LSEG-1);
  if (tid == 0) cnt_s = (b < NB) ? LOADU((unsigned*)(ws + OFF_BCNT) + b*16) : 0u;
  __syncthreads();
  unsigned cntb = cnt_s;
  bool valid = false; int a = 0;
  if (b < NB && (unsigned)i < cntb && cntb <= LSEG){
    valid = true;
    a = (int)((unsigned*)(ws + OFF_LIST))[b*LSEG + i];
  }
  // ---- phase A: resolve assignment, feed per-gt maxima ----
  int ns = 0; float av = 0.f;
  int loc=0, W=80, lvl=0, hw=6400; float sfac=8.f;
  if (valid){
    unsigned bits = ((const unsigned*)(ws + OFF_MPOS))[(size_t)b*A_TOT + a];
    locate(a, loc, W, sfac, lvl, hw);
    float4 pg = ((const float4*)(ws + OFF_PBOX))[(size_t)b*A_TOT + a];
    float px1 = pg.x*sfac, py1 = pg.y*sfac, px2 = pg.z*sfac, py2 = pg.w*sfac;
    float atp = atanf((px2-px1)/(py2-py1+CEPS));
    if (__popc(bits) == 1){ ns = __ffs(bits) - 1; }
    else {
      float bv = -1.f; ns = 0;
      for (int nn = 0; nn < NG; nn++){
        const float* g = ws + OFF_GTBOX + (b*NG + nn)*4;
        float atg = ws[OFF_ATANGT + b*NG + nn];
        float o = fmaxf(ciou_gp(g[0],g[1],g[2],g[3],atg, px1,py1,px2,py2,atp), 0.f);
        if (o > bv){ bv = o; ns = nn; }
      }
    }
    const float* g = ws + OFF_GTBOX + (b*NG + ns)*4;
    float atg = ws[OFF_ATANGT + b*NG + ns];
    float o = fmaxf(ciou_gp(g[0],g[1],g[2],g[3],atg, px1,py1,px2,py2,atp), 0.f);
    int lab = ((const int*)(ws + OFF_GTLAB))[b*NG + ns];
    float l = level_ptr(p3,p4,p5,lvl)[((size_t)b*hw + loc)*NCH + 64 + lab];
    float sc = __frcp_rn(1.f + __expf(-l));
    float o2 = o*o;
    av = sqrtf(sc)*o2*o2*o2;
    unsigned* pm = (unsigned*)(ws + OFF_POSM) + (b*NG + ns)*8;
    atomicMax(pm + 0, __float_as_uint(av));
    atomicMax(pm + 1, __float_as_uint(o));
  }
  // block 0: fold softplus partials (independent work)
  if (blockIdx.x == 0){
    float v = 0.f;
    for (int j = tid; j < NBLK2; j += 256) v += (ws + OFF_PART2)[j];
    #pragma unroll
    for (int st = 1; st < 64; st <<= 1) v += __shfl_xor(v, st);
    if (lane == 0) redw[wid] = v;
    __syncthreads();
    if (tid == 0)
      __hip_atomic_store(ws + OFF_ACC + 0, redw[0]+redw[1]+redw[2]+redw[3],
                         __ATOMIC_RELEASE, __HIP_MEMORY_SCOPE_AGENT);
    __syncthreads();
  }
  // ---- grid barrier (32 co-resident blocks): RMW arrive, LOAD poll ----
  __syncthreads();
  if (tid == 0){
    __threadfence();
    __hip_atomic_fetch_add((unsigned*)(ws + OFF_CTRL) + 1, 1u,
                           __ATOMIC_ACQ_REL, __HIP_MEMORY_SCOPE_AGENT);
    while (LOADU((unsigned*)(ws + OFF_CTRL) + 1) < K56_BLOCKS){ __builtin_amdgcn_s_sleep(1); }
  }
  __syncthreads();
  __threadfence();
  // ---- phase B: losses ----
  float bcec = 0.f, boxl = 0.f, dfll = 0.f, tsc = 0.f;
  if (valid){
    unsigned* pm = (unsigned*)(ws + OFF_POSM) + (b*NG + ns)*8;
    float pa = __uint_as_float(LOADU(pm + 0));
    float po = __uint_as_float(LOADU(pm + 1));
    float norm = av * po / (pa + EPSF);
    const float* row = level_ptr(p3,p4,p5,lvl) + ((size_t)b*hw + loc)*NCH;
    int lab = ((const int*)(ws + OFF_GTLAB))[b*NG + ns];
    if (lab < 0) lab = 0;
    tsc = norm;
    bcec = -row[64 + lab]*norm;
    float4 pb = ((const float4*)(ws + OFF_PBOX))[(size_t)b*A_TOT + a];
    const float* g = ws + OFF_GTBOX + (b*NG + ns)*4;
    float inv_s = 1.f/sfac;
    float tx1 = g[0]*inv_s, ty1 = g[1]*inv_s, tx2 = g[2]*inv_s, ty2 = g[3]*inv_s;
    float w1 = pb.z-pb.x, h1 = pb.w-pb.y+CEPS;
    float w2 = tx2-tx1,   h2 = ty2-ty1+CEPS;
    float iw = fmaxf(fminf(pb.z,tx2)-fmaxf(pb.x,tx1), 0.f);
    float ih = fmaxf(fminf(pb.w,ty2)-fmaxf(pb.y,ty1), 0.f);
    float inter = iw*ih;
    float uni = w1*h1 + w2*h2 - inter + CEPS;
    float iou = inter/uni;
    float cw = fmaxf(pb.z,tx2)-fminf(pb.x,tx1);
    float ch = fmaxf(pb.w,ty2)-fminf(pb.y,ty1);
    float c2 = cw*cw + ch*ch + CEPS;
    float dx = tx1+tx2-pb.x-pb.z, dy = ty1+ty2-pb.y-pb.w;
    float rho2 = (dx*dx + dy*dy)*0.25f;
    float dv = atanf(w2/h2) - atanf(w1/h1);
    float v = INV_PI2_4*dv*dv;
    float al = v/(v - iou + (1.f + CEPS));
    float ci = iou - (rho2/c2 + v*al);
    boxl = (1.f - ci)*norm;
    float ax = (loc % W) + 0.5f, ay = (loc / W) + 0.5f;
    float ltrb[4] = {ax - tx1, ay - ty1, tx2 - ax, ty2 - ay};
    float ds = 0.f;
    #pragma unroll
    for (int f = 0; f < 4; f++){
      float val = fminf(fmaxf(ltrb[f], 0.f), (float)NDFL - 1.01f);
      int tl = (int)val;
      float wl = (float)(tl + 1) - val;
      float x[16];
      const float4* r4 = (const float4*)(row + f*16);
      #pragma unroll
      for (int q = 0; q < 4; q++){ float4 vv = r4[q]; x[q*4]=vv.x; x[q*4+1]=vv.y; x[q*4+2]=vv.z; x[q*4+3]=vv.w; }
      float m = x[0];
      #pragma unroll
      for (int j = 1; j < 16; j++) m = fmaxf(m, x[j]);
      float se = 0.f;
      #pragma unroll
      for (int j = 0; j < 16; j++) se += __expf(x[j]-m);
      float lse = m + __logf(se);
      float xl = 0.f, xr = 0.f;
      #pragma unroll
      for (int j = 0; j < 16; j++){
        xl = (j == tl)   ? x[j] : xl;
        xr = (j == tl+1) ? x[j] : xr;
      }
      ds += (lse - xl)*wl + (lse - xr)*(1.f - wl);
    }
    dfll = ds*0.25f*norm;
  }
  float vals[4] = {bcec, boxl, dfll, tsc};
  #pragma unroll
  for (int q = 0; q < 4; q++){
    float v = vals[q];
    #pragma unroll
    for (int st = 1; st < 64; st <<= 1) v += __shfl_xor(v, st);
    if (lane == 0) redw[wid*4 + q] = v;
  }
  if (tid == 0) lastf = 0;
  __syncthreads();
  if (tid < 4){
    float v = redw[tid] + redw[4+tid] + redw[8+tid] + redw[12+tid];
    __hip_atomic_store(ws + OFF_PART6 + blockIdx.x*4 + tid, v,
                       __ATOMIC_RELEASE, __HIP_MEMORY_SCOPE_AGENT);
  }
  __syncthreads();
  if (tid == 0){
    __threadfence();
    unsigned tkt = __hip_atomic_fetch_add((unsigned*)(ws + OFF_CTRL) + 2, 1u,
                                          __ATOMIC_ACQ_REL, __HIP_MEMORY_SCOPE_AGENT);
    if (tkt == K56_BLOCKS - 1) lastf = 1;
  }
  __syncthreads();
  if (lastf){
    if (tid < 4) fin[tid] = 0.f;
    __syncthreads();
    if (tid < 4*K56_BLOCKS){
      float v = LOADF(ws + OFF_PART6 + tid);
      atomicAdd(&fin[tid & 3], v);
    }
    __syncthreads();
    if (tid == 0){
      float sp = LOADF(ws + OFF_ACC + 0);
      float tss = fmaxf(fin[3], 1.f);
      out[0] = (0.5f*(sp + fin[0]) + 7.5f*fin[1] + 1.5f*fin[2]) / tss;
    }
  }
}

extern "C" void kernel_launch(void* const* d_in, const int* in_sizes, int n_in,
                              void* d_out, int out_size, void* d_ws, size_t ws_size,
                              hipStream_t stream) {
  const float* p3 = (const float*)d_in[0];
  const float* p4 = (const float*)d_in[1];
  const float* p5 = (const float*)d_in[2];
  const float* tg = (const float*)d_in[3];
  int nt = in_sizes[3] / 6;
  float* ws = (float*)d_ws;
  float* out = (float*)d_out;

  k2x<<<NBLK2 + 1, 256, 0, stream>>>(p3, p4, p5, tg, nt, ws);
  k4x<<<64, 512, 0, stream>>>(p3, p4, p5, ws);
  k56x<<<K56_BLOCKS, 256, 0, stream>>>(p3, p4, p5, ws, out);
}

// Round 13
// 61.744 us; speedup vs baseline: 1.4408x; 1.2426x over previous
//
#include <hip/hip_runtime.h>
#include <math.h>

#define A_TOT 8400
#define NB 16
#define NG 32
#define NCH 144
#define NDFL 16
#define EPSF 1e-9f
#define CEPS 1e-7f
#define INV_PI2_4 0.40528473456935109f  /* 4/pi^2 */
#define NBLK2 2100
#define LSEG 512
#define K56_BLOCKS 32
#define K4CAP 1024

#define LOADU(p)  __hip_atomic_load((p), __ATOMIC_ACQUIRE, __HIP_MEMORY_SCOPE_AGENT)
#define LOADF(p)  __hip_atomic_load((p), __ATOMIC_ACQUIRE, __HIP_MEMORY_SCOPE_AGENT)

// workspace layout (float32 indices)
#define OFF_GTBOX   0            /* NB*NG*4 = 2048 */
#define OFF_GTLAB   2048         /* 512 */
#define OFF_MASKGT  2560         /* 512 */
#define OFF_ATANGT  3072         /* 512 */
#define OFF_ACC     3584         /* 8: [0]=softplus total */
#define OFF_CTRL    3592         /* 8 u32: [1]=barrierA [2]=ticketB */
#define OFF_BCNT    3600         /* 16 counters, stride 16 u32 = 256 */
#define OFF_PART2   3856         /* 2112 per-block softplus partials */
#define OFF_PART6   5968         /* 128 k56 per-block partials */
#define OFF_POSM    6224         /* 512 gts x 8 floats: [0]=posAl [1]=posOv */
#define OFF_PBOX    10320        /* NB*A*4 grid units */
#define OFF_MPOS    547920       /* NB*A u32 */
#define OFF_LIST    682320       /* NB*LSEG u32 anchor ids */

__device__ __forceinline__ void locate(int a, int& loc, int& W, float& s, int& lvl, int& hw){
  if (a < 6400)      { lvl = 0; loc = a;        W = 80; s = 8.f;  hw = 6400; }
  else if (a < 8000) { lvl = 1; loc = a - 6400; W = 40; s = 16.f; hw = 1600; }
  else               { lvl = 2; loc = a - 8000; W = 20; s = 32.f; hw = 400;  }
}

__device__ __forceinline__ const float* level_ptr(const float* p3, const float* p4, const float* p5, int lvl){
  return lvl == 0 ? p3 : (lvl == 1 ? p4 : p5);
}

__device__ __forceinline__ float ciou_gp(float gx1,float gy1,float gx2,float gy2,float atg,
                                         float px1,float py1,float px2,float py2,float atp){
  float w1 = gx2-gx1, h1 = gy2-gy1+CEPS;
  float w2 = px2-px1, h2 = py2-py1+CEPS;
  float iw = fmaxf(fminf(gx2,px2)-fmaxf(gx1,px1), 0.f);
  float ih = fmaxf(fminf(gy2,py2)-fmaxf(gy1,py1), 0.f);
  float inter = iw*ih;
  float uni = w1*h1 + w2*h2 - inter + CEPS;
  float iou = inter/uni;
  float cw = fmaxf(gx2,px2)-fminf(gx1,px1);
  float ch = fmaxf(gy2,py2)-fminf(gy1,py1);
  float c2 = cw*cw + ch*ch + CEPS;
  float dx = px1+px2-gx1-gx2, dy = py1+py2-gy1-gy2;
  float rho2 = (dx*dx + dy*dy)*0.25f;
  float dv = atp - atg;
  float v = INV_PI2_4*dv*dv;
  float al = v/(v - iou + (1.f + CEPS));
  return iou - (rho2/c2 + v*al);
}

// ============ kernel A: barrier-light full-input pass + (last block) prep =======
__global__ __launch_bounds__(256) void k2x(const float* __restrict__ p3, const float* __restrict__ p4,
                          const float* __restrict__ p5, const float* __restrict__ tgt, int nt,
                          float* __restrict__ ws){
  int tid = threadIdx.x;
  int bx = blockIdx.x;
  if (bx == NBLK2){
    __shared__ int simg[256];
    float* gtbox  = ws + OFF_GTBOX;
    int*   gtlab  = (int*)(ws + OFF_GTLAB);
    float* maskgt = ws + OFF_MASKGT;
    float* atangt = ws + OFF_ATANGT;
    for (int i = tid; i < NB*NG*4; i += 256) gtbox[i] = 0.f;
    for (int i = tid; i < NB*NG; i += 256) gtlab[i] = 0;
    if (tid < 8){ (ws + OFF_ACC)[tid] = 0.f; ((unsigned*)(ws + OFF_CTRL))[tid] = 0u; }
    for (int i = tid; i < 256;  i += 256) ((unsigned*)(ws + OFF_BCNT))[i] = 0u;
    for (int i = tid; i < NB*NG*8; i += 256) (ws + OFF_POSM)[i] = 0.f;
    for (int i = tid; i < nt && i < 256; i += 256) simg[i] = (int)tgt[i*6];
    __syncthreads();
    for (int i = tid; i < nt && i < 256; i += 256){
      int b = simg[i];
      int r = 0;
      for (int j = 0; j < i; j++) r += (simg[j] == b);
      if (b >= 0 && b < NB && r < NG){
        float cls = tgt[i*6+1];
        float cx = tgt[i*6+2]*640.f, cy = tgt[i*6+3]*640.f;
        float w  = tgt[i*6+4]*640.f, h  = tgt[i*6+5]*640.f;
        int o = (b*NG + r)*4;
        gtbox[o+0] = cx - 0.5f*w; gtbox[o+1] = cy - 0.5f*h;
        gtbox[o+2] = cx + 0.5f*w; gtbox[o+3] = cy + 0.5f*h;
        gtlab[b*NG + r] = (int)cls;
      }
    }
    __syncthreads();
    for (int i = tid; i < NB*NG; i += 256){
      float x1 = gtbox[i*4], y1 = gtbox[i*4+1], x2 = gtbox[i*4+2], y2 = gtbox[i*4+3];
      maskgt[i] = ((x1+y1+x2+y2) > 0.f) ? 1.f : 0.f;
      atangt[i] = atanf((x2-x1)/(y2-y1+CEPS));
    }
    return;
  }
  __shared__ float redw[4];
  {
    int mp = bx*256 + tid;
    if (mp < NB*A_TOT) ((unsigned*)(ws + OFF_MPOS))[mp] = 0u;
  }
  const float* base; int grow0, hw, W, lvloff;
  if (bx < 1600)      { base = p3; grow0 = bx*64;        hw = 6400; W = 80; lvloff = 0; }
  else if (bx < 2000) { base = p4; grow0 = (bx-1600)*64; hw = 1600; W = 40; lvloff = 6400; }
  else                { base = p5; grow0 = (bx-2000)*64; hw = 400;  W = 20; lvloff = 8000; }

  const float4* src = (const float4*)base + (size_t)grow0*36;
  // DFL decode: thread t -> row r = t>>2, side f = t&3; 64B/lane contiguous
  {
    int r = tid >> 2, f = tid & 3;
    const float4* rp = src + r*36 + f*4;
    float4 v0 = rp[0], v1 = rp[1], v2 = rp[2], v3 = rp[3];
    float m = v0.x;
    m = fmaxf(m, v0.y); m = fmaxf(m, v0.z); m = fmaxf(m, v0.w);
    m = fmaxf(m, v1.x); m = fmaxf(m, v1.y); m = fmaxf(m, v1.z); m = fmaxf(m, v1.w);
    m = fmaxf(m, v2.x); m = fmaxf(m, v2.y); m = fmaxf(m, v2.z); m = fmaxf(m, v2.w);
    m = fmaxf(m, v3.x); m = fmaxf(m, v3.y); m = fmaxf(m, v3.z); m = fmaxf(m, v3.w);
    float e, se, swe;
    e = __expf(v0.x - m); se = e;            swe = 0.f;
    e = __expf(v0.y - m); se += e;           swe += e;
    e = __expf(v0.z - m); se += e;           swe = fmaf(2.f,  e, swe);
    e = __expf(v0.w - m); se += e;           swe = fmaf(3.f,  e, swe);
    e = __expf(v1.x - m); se += e;           swe = fmaf(4.f,  e, swe);
    e = __expf(v1.y - m); se += e;           swe = fmaf(5.f,  e, swe);
    e = __expf(v1.z - m); se += e;           swe = fmaf(6.f,  e, swe);
    e = __expf(v1.w - m); se += e;           swe = fmaf(7.f,  e, swe);
    e = __expf(v2.x - m); se += e;           swe = fmaf(8.f,  e, swe);
    e = __expf(v2.y - m); se += e;           swe = fmaf(9.f,  e, swe);
    e = __expf(v2.z - m); se += e;           swe = fmaf(10.f, e, swe);
    e = __expf(v2.w - m); se += e;           swe = fmaf(11.f, e, swe);
    e = __expf(v3.x - m); se += e;           swe = fmaf(12.f, e, swe);
    e = __expf(v3.y - m); se += e;           swe = fmaf(13.f, e, swe);
    e = __expf(v3.z - m); se += e;           swe = fmaf(14.f, e, swe);
    e = __expf(v3.w - m); se += e;           swe = fmaf(15.f, e, swe);
    float pdf = __fdividef(swe, se);
    float s1 = __shfl_xor(pdf, 1);
    float s2 = __shfl_xor(pdf, 2);
    float s3 = __shfl_xor(pdf, 3);
    if (f == 0){
      int grow = grow0 + r;
      int b = grow / hw, loc = grow - b*hw;
      float ax = (loc % W) + 0.5f, ay = (loc / W) + 0.5f;
      float4 pb;
      pb.x = ax - pdf; pb.y = ay - s1; pb.z = ax + s2; pb.w = ay + s3;
      ((float4*)(ws + OFF_PBOX))[(size_t)b*A_TOT + lvloff + loc] = pb;
    }
  }
  // softplus over score channels
  float sp = 0.f;
  #pragma unroll
  for (int i = 0; i < 5; i++){
    int id = i*256 + tid;
    int r = id/20, q = id - r*20;
    float4 v = src[r*36 + 16 + q];
    #pragma unroll
    for (int e2 = 0; e2 < 4; e2++){
      float x = (&v.x)[e2];
      float ex = __expf(-fabsf(x));
      sp += fmaxf(x, 0.f) + __logf(1.f + ex);
    }
  }
  #pragma unroll
  for (int st = 1; st < 64; st <<= 1) sp += __shfl_xor(sp, st);
  int wid = tid >> 6, lane = tid & 63;
  if (lane == 0) redw[wid] = sp;
  __syncthreads();
  if (tid == 0) (ws + OFF_PART2)[bx] = redw[0]+redw[1]+redw[2]+redw[3];
}

// ============ kernel B: block-per-(b,n) top-10, packed-key selection ============
__global__ __launch_bounds__(256) void k4x(const float* __restrict__ p3, const float* __restrict__ p4,
                        const float* __restrict__ p5, float* __restrict__ ws){
  __shared__ unsigned long long wk[4];
  int tid = threadIdx.x;
  int lane = tid & 63, wid = tid >> 6;
  int bx = blockIdx.x;
  int b = bx >> 5, n = bx & 31;
  float mk = ws[OFF_MASKGT + b*NG + n];
  if (mk <= 0.f) return;
  int lab = ((const int*)(ws + OFF_GTLAB))[b*NG + n];
  int ch = 64 + lab;
  float atg = ws[OFF_ATANGT + b*NG + n];
  const float* gt = ws + OFF_GTBOX + (b*NG + n)*4;
  float gx1 = gt[0], gy1 = gt[1], gx2 = gt[2], gy2 = gt[3];

  int clo0 = max(0, (int)floorf(gx1*0.125f   - 0.5f));
  int chi0 = min(79,(int)ceilf (gx2*0.125f   - 0.5f));
  int rlo0 = max(0, (int)floorf(gy1*0.125f   - 0.5f));
  int rhi0 = min(79,(int)ceilf (gy2*0.125f   - 0.5f));
  int clo1 = max(0, (int)floorf(gx1*0.0625f  - 0.5f));
  int chi1 = min(39,(int)ceilf (gx2*0.0625f  - 0.5f));
  int rlo1 = max(0, (int)floorf(gy1*0.0625f  - 0.5f));
  int rhi1 = min(39,(int)ceilf (gy2*0.0625f  - 0.5f));
  int clo2 = max(0, (int)floorf(gx1*0.03125f - 0.5f));
  int chi2 = min(19,(int)ceilf (gx2*0.03125f - 0.5f));
  int rlo2 = max(0, (int)floorf(gy1*0.03125f - 0.5f));
  int rhi2 = min(19,(int)ceilf (gy2*0.03125f - 0.5f));
  int nc0 = chi0-clo0+1, nr0 = rhi0-rlo0+1;
  int nc1 = chi1-clo1+1, nr1 = rhi1-rlo1+1;
  int nc2 = chi2-clo2+1, nr2 = rhi2-rlo2+1;
  int cnt0 = (nc0>0 && nr0>0) ? nc0*nr0 : 0;
  int cnt1 = (nc1>0 && nr1>0) ? nc1*nr1 : 0;
  int cnt2 = (nc2>0 && nr2>0) ? nc2*nr2 : 0;
  if (16+cnt0 > K4CAP)           cnt0 = K4CAP-16;
  if (16+cnt0+cnt1 > K4CAP)      cnt1 = K4CAP-16-cnt0;
  if (16+cnt0+cnt1+cnt2 > K4CAP) cnt2 = K4CAP-16-cnt0-cnt1;
  int b1 = 16 + cnt0, b2 = b1 + cnt1;
  int tot = b2 + cnt2;

  // each thread owns 4 candidate slots; key = (m_bits<<32)|(0xFFFFFFFF-aidx)
  unsigned long long key[4];
  #pragma unroll
  for (int j = 0; j < 4; j++){
    key[j] = 0ull;
    int c = j*256 + tid;
    if (c < tot){
      int aidx, loc, W, hw; float s; const float* bp; bool dup = false;
      if (c < 16)     { aidx = c; loc = c; W = 80; s = 8.f;  hw = 6400; bp = p3; }
      else if (c < b1){ int jj = c-16; int rr = jj/nc0; loc = (rlo0+rr)*80 + clo0 + (jj - rr*nc0);
                        aidx = loc;        W = 80; s = 8.f;  hw = 6400; bp = p3; dup = (aidx < 16); }
      else if (c < b2){ int jj = c-b1; int rr = jj/nc1; loc = (rlo1+rr)*40 + clo1 + (jj - rr*nc1);
                        aidx = 6400 + loc; W = 40; s = 16.f; hw = 1600; bp = p4; }
      else            { int jj = c-b2; int rr = jj/nc2; loc = (rlo2+rr)*20 + clo2 + (jj - rr*nc2);
                        aidx = 8000 + loc; W = 20; s = 32.f; hw = 400;  bp = p5; }
      if (!dup){
        float m = 0.f;
        float axi = ((loc % W) + 0.5f)*s, ayi = ((loc / W) + 0.5f)*s;
        float dmin = fminf(fminf(axi-gx1, ayi-gy1), fminf(gx2-axi, gy2-ayi));
        if (dmin > EPSF){
          float4 pg = ((const float4*)(ws + OFF_PBOX))[(size_t)b*A_TOT + aidx];
          float px1 = pg.x*s, py1 = pg.y*s, px2 = pg.z*s, py2 = pg.w*s;
          float atp = atanf((px2-px1)/(py2-py1+CEPS));
          float o = fmaxf(ciou_gp(gx1,gy1,gx2,gy2,atg, px1,py1,px2,py2,atp), 0.f);
          float l = bp[((size_t)b*hw + loc)*NCH + ch];
          float sc = __frcp_rn(1.f + __expf(-l));
          float o2 = o*o;
          m = sqrtf(sc)*o2*o2*o2;
        }
        key[j] = ((unsigned long long)__float_as_uint(m) << 32)
               | (unsigned long long)(0xFFFFFFFFu - (unsigned)aidx);
      }
    }
  }
  // 10 selection passes
  float top0m = 0.f;
  int mytop = -1;
  for (int k = 0; k < 10; k++){
    unsigned long long bk = key[0];
    #pragma unroll
    for (int j = 1; j < 4; j++) if (key[j] > bk) bk = key[j];
    #pragma unroll
    for (int st = 1; st < 64; st <<= 1){
      unsigned long long ok = __shfl_xor(bk, st);
      if (ok > bk) bk = ok;
    }
    if (lane == 0) wk[wid] = bk;
    __syncthreads();
    unsigned long long fk = wk[0];
    #pragma unroll
    for (int w = 1; w < 4; w++) if (wk[w] > fk) fk = wk[w];
    if (k == 0) top0m = __uint_as_float((unsigned)(fk >> 32));
    if (tid == k) mytop = (int)(0xFFFFFFFFu - (unsigned)(fk & 0xFFFFFFFFull));
    #pragma unroll
    for (int j = 0; j < 4; j++) if (key[j] == fk) key[j] = 0ull;
    __syncthreads();
  }
  // scatter (wave 0, lanes 0..9 hold winners)
  bool want = (tid < 64) && (lane < 10) && (top0m > EPSF) && (mytop >= 0) && (mytop < A_TOT);
  if (want){
    int loc, W, lvl, hw; float s;
    locate(mytop, loc, W, s, lvl, hw);
    float axi = ((loc % W) + 0.5f)*s, ayi = ((loc / W) + 0.5f)*s;
    float dmin = fminf(fminf(axi-gx1, ayi-gy1), fminf(gx2-axi, gy2-ayi));
    want = (dmin > EPSF);
  }
  if (tid < 64){
    unsigned old = 0u;
    if (want) old = atomicOr((unsigned*)(ws + OFF_MPOS) + (size_t)b*A_TOT + mytop, 1u << n);
    bool w2 = want && (old == 0u);
    unsigned long long m64 = __ballot(w2);
    if (w2){
      int lead = __ffsll((long long)m64) - 1;
      unsigned base = 0;
      if (lane == lead) base = atomicAdd((unsigned*)(ws + OFF_BCNT) + b*16, (unsigned)__popcll(m64));
      base = __shfl(base, lead);
      unsigned slot = base + (unsigned)__popcll(m64 & ((1ull << lane) - 1ull));
      if (slot < LSEG) ((unsigned*)(ws + OFF_LIST))[b*LSEG + slot] = (unsigned)mytop;
    }
  }
}

// ============ kernel C: resolve + internal barrier + losses + combine ===========
__global__ __launch_bounds__(256) void k56x(const float* __restrict__ p3, const float* __restrict__ p4,
                        const float* __restrict__ p5, float* __restrict__ ws, float* __restrict__ out){
  __shared__ float redw[16];
  __shared__ float fin[4];
  __shared__ int lastf;
  __shared__ unsigned cnt_s;
  int tid = threadIdx.x;
  int lane = tid & 63, wid = tid >> 6;
  int s_id = blockIdx.x*256 + tid;
  int b = s_id >> 9, i = s_id & (LSEG-1);
  if (tid == 0) cnt_s = (b < NB) ? LOADU((unsigned*)(ws + OFF_BCNT) + b*16) : 0u;
  __syncthreads();
  unsigned cntb = cnt_s;
  bool valid = false; int a = 0;
  if (b < NB && (unsigned)i < cntb && cntb <= LSEG){
    valid = true;
    a = (int)((unsigned*)(ws + OFF_LIST))[b*LSEG + i];
  }
  // ---- phase A: resolve assignment, feed per-gt maxima ----
  int ns = 0; float av = 0.f;
  int loc=0, W=80, lvl=0, hw=6400; float sfac=8.f;
  if (valid){
    unsigned bits = ((const unsigned*)(ws + OFF_MPOS))[(size_t)b*A_TOT + a];
    locate(a, loc, W, sfac, lvl, hw);
    float4 pg = ((const float4*)(ws + OFF_PBOX))[(size_t)b*A_TOT + a];
    float px1 = pg.x*sfac, py1 = pg.y*sfac, px2 = pg.z*sfac, py2 = pg.w*sfac;
    float atp = atanf((px2-px1)/(py2-py1+CEPS));
    if (__popc(bits) == 1){ ns = __ffs(bits) - 1; }
    else {
      float bv = -1.f; ns = 0;
      for (int nn = 0; nn < NG; nn++){
        const float* g = ws + OFF_GTBOX + (b*NG + nn)*4;
        float atg = ws[OFF_ATANGT + b*NG + nn];
        float o = fmaxf(ciou_gp(g[0],g[1],g[2],g[3],atg, px1,py1,px2,py2,atp), 0.f);
        if (o > bv){ bv = o; ns = nn; }
      }
    }
    const float* g = ws + OFF_GTBOX + (b*NG + ns)*4;
    float atg = ws[OFF_ATANGT + b*NG + ns];
    float o = fmaxf(ciou_gp(g[0],g[1],g[2],g[3],atg, px1,py1,px2,py2,atp), 0.f);
    int lab = ((const int*)(ws + OFF_GTLAB))[b*NG + ns];
    float l = level_ptr(p3,p4,p5,lvl)[((size_t)b*hw + loc)*NCH + 64 + lab];
    float sc = __frcp_rn(1.f + __expf(-l));
    float o2 = o*o;
    av = sqrtf(sc)*o2*o2*o2;
    unsigned* pm = (unsigned*)(ws + OFF_POSM) + (b*NG + ns)*8;
    atomicMax(pm + 0, __float_as_uint(av));
    atomicMax(pm + 1, __float_as_uint(o));
  }
  // block 0: fold softplus partials (independent work)
  if (blockIdx.x == 0){
    float v = 0.f;
    for (int j = tid; j < NBLK2; j += 256) v += (ws + OFF_PART2)[j];
    #pragma unroll
    for (int st = 1; st < 64; st <<= 1) v += __shfl_xor(v, st);
    if (lane == 0) redw[wid] = v;
    __syncthreads();
    if (tid == 0)
      __hip_atomic_store(ws + OFF_ACC + 0, redw[0]+redw[1]+redw[2]+redw[3],
                         __ATOMIC_RELEASE, __HIP_MEMORY_SCOPE_AGENT);
    __syncthreads();
  }
  // ---- grid barrier (32 co-resident blocks): RMW arrive, LOAD poll ----
  __syncthreads();
  if (tid == 0){
    __threadfence();
    __hip_atomic_fetch_add((unsigned*)(ws + OFF_CTRL) + 1, 1u,
                           __ATOMIC_ACQ_REL, __HIP_MEMORY_SCOPE_AGENT);
    while (LOADU((unsigned*)(ws + OFF_CTRL) + 1) < K56_BLOCKS){ __builtin_amdgcn_s_sleep(1); }
  }
  __syncthreads();
  __threadfence();
  // ---- phase B: losses ----
  float bcec = 0.f, boxl = 0.f, dfll = 0.f, tsc = 0.f;
  if (valid){
    unsigned* pm = (unsigned*)(ws + OFF_POSM) + (b*NG + ns)*8;
    float pa = __uint_as_float(LOADU(pm + 0));
    float po = __uint_as_float(LOADU(pm + 1));
    float norm = av * po / (pa + EPSF);
    const float* row = level_ptr(p3,p4,p5,lvl) + ((size_t)b*hw + loc)*NCH;
    int lab = ((const int*)(ws + OFF_GTLAB))[b*NG + ns];
    if (lab < 0) lab = 0;
    tsc = norm;
    bcec = -row[64 + lab]*norm;
    float4 pb = ((const float4*)(ws + OFF_PBOX))[(size_t)b*A_TOT + a];
    const float* g = ws + OFF_GTBOX + (b*NG + ns)*4;
    float inv_s = 1.f/sfac;
    float tx1 = g[0]*inv_s, ty1 = g[1]*inv_s, tx2 = g[2]*inv_s, ty2 = g[3]*inv_s;
    float w1 = pb.z-pb.x, h1 = pb.w-pb.y+CEPS;
    float w2 = tx2-tx1,   h2 = ty2-ty1+CEPS;
    float iw = fmaxf(fminf(pb.z,tx2)-fmaxf(pb.x,tx1), 0.f);
    float ih = fmaxf(fminf(pb.w,ty2)-fmaxf(pb.y,ty1), 0.f);
    float inter = iw*ih;
    float uni = w1*h1 + w2*h2 - inter + CEPS;
    float iou = inter/uni;
    float cw = fmaxf(pb.z,tx2)-fminf(pb.x,tx1);
    float ch = fmaxf(pb.w,ty2)-fminf(pb.y,ty1);
    float c2 = cw*cw + ch*ch + CEPS;
    float dx = tx1+tx2-pb.x-pb.z, dy = ty1+ty2-pb.y-pb.w;
    float rho2 = (dx*dx + dy*dy)*0.25f;
    float dv = atanf(w2/h2) - atanf(w1/h1);
    float v = INV_PI2_4*dv*dv;
    float al = v/(v - iou + (1.f + CEPS));
    float ci = iou - (rho2/c2 + v*al);
    boxl = (1.f - ci)*norm;
    float ax = (loc % W) + 0.5f, ay = (loc / W) + 0.5f;
    float ltrb[4] = {ax - tx1, ay - ty1, tx2 - ax, ty2 - ay};
    float ds = 0.f;
    #pragma unroll
    for (int f = 0; f < 4; f++){
      float val = fminf(fmaxf(ltrb[f], 0.f), (float)NDFL - 1.01f);
      int tl = (int)val;
      float wl = (float)(tl + 1) - val;
      float x[16];
      const float4* r4 = (const float4*)(row + f*16);
      #pragma unroll
      for (int q = 0; q < 4; q++){ float4 vv = r4[q]; x[q*4]=vv.x; x[q*4+1]=vv.y; x[q*4+2]=vv.z; x[q*4+3]=vv.w; }
      float m = x[0];
      #pragma unroll
      for (int j = 1; j < 16; j++) m = fmaxf(m, x[j]);
      float se = 0.f;
      #pragma unroll
      for (int j = 0; j < 16; j++) se += __expf(x[j]-m);
      float lse = m + __logf(se);
      float xl = 0.f, xr = 0.f;
      #pragma unroll
      for (int j = 0; j < 16; j++){
        xl = (j == tl)   ? x[j] : xl;
        xr = (j == tl+1) ? x[j] : xr;
      }
      ds += (lse - xl)*wl + (lse - xr)*(1.f - wl);
    }
    dfll = ds*0.25f*norm;
  }
  float vals[4] = {bcec, boxl, dfll, tsc};
  #pragma unroll
  for (int q = 0; q < 4; q++){
    float v = vals[q];
    #pragma unroll
    for (int st = 1; st < 64; st <<= 1) v += __shfl_xor(v, st);
    if (lane == 0) redw[wid*4 + q] = v;
  }
  if (tid == 0) lastf = 0;
  __syncthreads();
  if (tid < 4){
    float v = redw[tid] + redw[4+tid] + redw[8+tid] + redw[12+tid];
    __hip_atomic_store(ws + OFF_PART6 + blockIdx.x*4 + tid, v,
                       __ATOMIC_RELEASE, __HIP_MEMORY_SCOPE_AGENT);
  }
  __syncthreads();
  if (tid == 0){
    __threadfence();
    unsigned tkt = __hip_atomic_fetch_add((unsigned*)(ws + OFF_CTRL) + 2, 1u,
                                          __ATOMIC_ACQ_REL, __HIP_MEMORY_SCOPE_AGENT);
    if (tkt == K56_BLOCKS - 1) lastf = 1;
  }
  __syncthreads();
  if (lastf){
    if (tid < 4) fin[tid] = 0.f;
    __syncthreads();
    if (tid < 4*K56_BLOCKS){
      float v = LOADF(ws + OFF_PART6 + tid);
      atomicAdd(&fin[tid & 3], v);
    }
    __syncthreads();
    if (tid == 0){
      float sp = LOADF(ws + OFF_ACC + 0);
      float tss = fmaxf(fin[3], 1.f);
      out[0] = (0.5f*(sp + fin[0]) + 7.5f*fin[1] + 1.5f*fin[2]) / tss;
    }
  }
}

extern "C" void kernel_launch(void* const* d_in, const int* in_sizes, int n_in,
                              void* d_out, int out_size, void* d_ws, size_t ws_size,
                              hipStream_t stream) {
  const float* p3 = (const float*)d_in[0];
  const float* p4 = (const float*)d_in[1];
  const float* p5 = (const float*)d_in[2];
  const float* tg = (const float*)d_in[3];
  int nt = in_sizes[3] / 6;
  float* ws = (float*)d_ws;
  float* out = (float*)d_out;

  k2x<<<NBLK2 + 1, 256, 0, stream>>>(p3, p4, p5, tg, nt, ws);
  k4x<<<NB*NG, 256, 0, stream>>>(p3, p4, p5, ws);
  k56x<<<K56_BLOCKS, 256, 0, stream>>>(p3, p4, p5, ws, out);
}